// Round 1
// baseline (865.262 us; speedup 1.0000x reference)
//
#include <hip/hip_runtime.h>

// ---------------- types / helpers ----------------
typedef short bf8s __attribute__((ext_vector_type(8)));   // 8 bf16 (4 VGPRs)
typedef float f32x4 __attribute__((ext_vector_type(4)));

#define MFMA16(a, b, c) __builtin_amdgcn_mfma_f32_16x16x32_bf16(a, b, c, 0, 0, 0)

constexpr int S_ = 512, HID_ = 128, B_ = 128, M_ = B_ * S_;

__device__ inline short f2bf(float f) {  // fp32 -> bf16 (RNE)
  unsigned u = __float_as_uint(f);
  u = (u + 0x7fffu + ((u >> 16) & 1u)) >> 16;
  return (short)u;
}
__device__ inline float bf2f(short s) {
  return __uint_as_float(((unsigned)(unsigned short)s) << 16);
}

__device__ inline float block_sum256(float v) {
  __shared__ float red[4];
  #pragma unroll
  for (int m = 32; m >= 1; m >>= 1) v += __shfl_xor(v, m);
  __syncthreads();
  if ((threadIdx.x & 63) == 0) red[threadIdx.x >> 6] = v;
  __syncthreads();
  return red[0] + red[1] + red[2] + red[3];
}

// matrix table: 0..7 = {q,k,v,ao}x{l0,l1} (16384), 8..9 = iw (65536),
// 10..11 = fow (65536), 12 = clf (256)
__device__ inline void mat_info(int mat, const float* qw, const float* kw,
                                const float* vw, const float* aow, const float* iw,
                                const float* fw, const float* cw,
                                const float** src, int* n, int* doff) {
  if (mat < 8) {
    const float* t[4] = {qw, kw, vw, aow};
    *src = t[mat >> 1] + (mat & 1) * 16384; *n = 16384; *doff = mat * 16384;
  } else if (mat < 10) {
    *src = iw + (mat - 8) * 65536; *n = 65536; *doff = 131072 + (mat - 8) * 65536;
  } else if (mat < 12) {
    *src = fw + (mat - 10) * 65536; *n = 65536; *doff = 262144 + (mat - 10) * 65536;
  } else {
    *src = cw; *n = 256; *doff = 393216;
  }
}

// ---------------- quantization (3 stages) ----------------
__global__ __launch_bounds__(256) void k_q1(const float* qw, const float* kw,
    const float* vw, const float* aow, const float* iw, const float* fw,
    const float* cw, float* scr) {
  const float* src; int n, doff;
  mat_info(blockIdx.y, qw, kw, vw, aow, iw, fw, cw, &src, &n, &doff);
  float s = 0.f;
  for (int i = blockIdx.x * 256 + threadIdx.x; i < n; i += 16 * 256) s += fabsf(src[i]);
  s = block_sum256(s);
  if (threadIdx.x == 0) atomicAdd(&scr[blockIdx.y], s);
}

__global__ __launch_bounds__(256) void k_q2(const float* qw, const float* kw,
    const float* vw, const float* aow, const float* iw, const float* fw,
    const float* cw, float* scr) {
  const float* src; int n, doff;
  mat_info(blockIdx.y, qw, kw, vw, aow, iw, fw, cw, &src, &n, &doff);
  float delta = 0.7f * scr[blockIdx.y] / (float)n;
  float s2 = 0.f, c2 = 0.f;
  for (int i = blockIdx.x * 256 + threadIdx.x; i < n; i += 16 * 256) {
    float a = fabsf(src[i]);
    if (a > delta) { s2 += a; c2 += 1.f; }
  }
  s2 = block_sum256(s2);
  c2 = block_sum256(c2);
  if (threadIdx.x == 0) {
    atomicAdd(&scr[16 + blockIdx.y], s2);
    atomicAdd(&scr[32 + blockIdx.y], c2);
  }
}

__global__ __launch_bounds__(256) void k_q3(const float* qw, const float* kw,
    const float* vw, const float* aow, const float* iw, const float* fw,
    const float* cw, const float* scr, short* WQ) {
  const float* src; int n, doff;
  mat_info(blockIdx.y, qw, kw, vw, aow, iw, fw, cw, &src, &n, &doff);
  float delta = 0.7f * scr[blockIdx.y] / (float)n;
  float alpha = scr[16 + blockIdx.y] / fmaxf(scr[32 + blockIdx.y], 1.f);
  for (int i = blockIdx.x * 256 + threadIdx.x; i < n; i += 16 * 256) {
    float w = src[i];
    WQ[doff + i] = (fabsf(w) > delta) ? f2bf(w > 0.f ? alpha : -alpha) : (short)0;
  }
}

// ---------------- embedding + LN ----------------
__global__ __launch_bounds__(256) void k_embed(const int* __restrict__ ids,
    const float* __restrict__ tok, const float* __restrict__ pos,
    const float* __restrict__ g, const float* __restrict__ bb,
    float* xf, short* xb) {
  int wave = threadIdx.x >> 6, lane = threadIdx.x & 63;
  int t = blockIdx.x * 4 + wave;
  int s = t & (S_ - 1);
  int id = ids[t];
  float e0 = tok[(size_t)id * HID_ + lane] + pos[(size_t)s * HID_ + lane];
  float e1 = tok[(size_t)id * HID_ + 64 + lane] + pos[(size_t)s * HID_ + 64 + lane];
  float sum = e0 + e1, ssq = e0 * e0 + e1 * e1;
  #pragma unroll
  for (int m = 32; m >= 1; m >>= 1) {
    sum += __shfl_xor(sum, m);
    ssq += __shfl_xor(ssq, m);
  }
  float mean = sum / 128.f;
  float var = ssq / 128.f - mean * mean;
  float rs = rsqrtf(var + 1e-5f);
  float v0 = (e0 - mean) * rs * g[lane] + bb[lane];
  float v1 = (e1 - mean) * rs * g[64 + lane] + bb[64 + lane];
  size_t o = (size_t)t * HID_;
  xf[o + lane] = v0; xf[o + 64 + lane] = v1;
  xb[o + lane] = f2bf(v0); xb[o + 64 + lane] = f2bf(v1);
}

// ---------------- generic MFMA linear ----------------
// block = 64 tokens x 128 outs (wave = 16 tokens x 128 outs, 8 C tiles)
// mode 0: bias -> bf16 out;  1: bias+relu -> bf16 out;
// mode 2: bias + residual + LayerNorm -> outf (fp32) + outb (bf16)   [needs grid.y==1]
__global__ __launch_bounds__(256) void k_linear(
    const short* __restrict__ A, const short* __restrict__ W,
    const float* __restrict__ bias, int K, int out_stride, int mode,
    short* outb, const float* resid, const float* __restrict__ lng,
    const float* __restrict__ lnb, float* outf) {
  int lane = threadIdx.x & 63, wave = threadIdx.x >> 6;
  int row16 = lane & 15, quad = lane >> 4;
  int tok0 = blockIdx.x * 64 + wave * 16;
  int nbase = blockIdx.y * 128;

  f32x4 acc[8] = {};
  const short* arow = A + (size_t)(tok0 + row16) * K + quad * 8;
  for (int kc = 0; kc < K; kc += 32) {
    bf8s a = *(const bf8s*)(arow + kc);
    #pragma unroll
    for (int ot = 0; ot < 8; ++ot) {
      bf8s b = *(const bf8s*)(W + (size_t)(nbase + ot * 16 + row16) * K + kc + quad * 8);
      acc[ot] = MFMA16(a, b, acc[ot]);
    }
  }

  int m0 = tok0 + quad * 4;  // C/D layout: row = quad*4+r, col = ot*16 + row16
  if (mode < 2) {
    #pragma unroll
    for (int ot = 0; ot < 8; ++ot) {
      int col = nbase + ot * 16 + row16;
      float bi = bias[col];
      #pragma unroll
      for (int r = 0; r < 4; ++r) {
        float v = acc[ot][r] + bi;
        if (mode == 1) v = fmaxf(v, 0.f);
        outb[(size_t)(m0 + r) * out_stride + col] = f2bf(v);
      }
    }
  } else {
    float sum[4] = {0, 0, 0, 0}, ssq[4] = {0, 0, 0, 0};
    #pragma unroll
    for (int ot = 0; ot < 8; ++ot) {
      int col = ot * 16 + row16;
      float bi = bias[col];
      #pragma unroll
      for (int r = 0; r < 4; ++r) {
        float v = acc[ot][r] + bi + resid[(size_t)(m0 + r) * HID_ + col];
        acc[ot][r] = v;
        sum[r] += v; ssq[r] += v * v;
      }
    }
    #pragma unroll
    for (int m = 1; m <= 8; m <<= 1) {
      #pragma unroll
      for (int r = 0; r < 4; ++r) {
        sum[r] += __shfl_xor(sum[r], m);
        ssq[r] += __shfl_xor(ssq[r], m);
      }
    }
    float mean[4], rstd[4];
    #pragma unroll
    for (int r = 0; r < 4; ++r) {
      mean[r] = sum[r] / 128.f;
      float var = ssq[r] / 128.f - mean[r] * mean[r];
      rstd[r] = rsqrtf(var + 1e-5f);
    }
    #pragma unroll
    for (int ot = 0; ot < 8; ++ot) {
      int col = ot * 16 + row16;
      float gg = lng[col], bb2 = lnb[col];
      #pragma unroll
      for (int r = 0; r < 4; ++r) {
        float v = (acc[ot][r] - mean[r]) * rstd[r] * gg + bb2;
        size_t idx = (size_t)(m0 + r) * HID_ + col;
        outf[idx] = v;
        outb[idx] = f2bf(v);
      }
    }
  }
}

// ---------------- flash attention (MFMA) ----------------
// grid = (S/64, H=2, B); block = 256 (4 waves x 16 queries)
__global__ __launch_bounds__(256) void k_attn(const short* __restrict__ Q,
    const short* __restrict__ Kb, const short* __restrict__ V, short* O) {
  constexpr float scale = 0.125f;  // 1/sqrt(64)
  __shared__ short Kl[32 * 72];    // 32 keys x 64 d, row stride 72 (pad)
  __shared__ short Vt[64 * 32];    // transposed: [d][key]
  __shared__ short Pl[4][16 * 32]; // per-wave P stash (16 q x 32 k)

  int tid = threadIdx.x, lane = tid & 63, wave = tid >> 6;
  int row16 = lane & 15, quad = lane >> 4;
  int b = blockIdx.z, h = blockIdx.y, q0 = blockIdx.x * 64;
  size_t base = (size_t)b * S_ * HID_ + h * 64;
  int skey = tid >> 3, sdg = tid & 7;  // staging: thread -> (key, d-group)

  const short* qrow = Q + base + (size_t)(q0 + wave * 16 + row16) * HID_ + quad * 8;
  bf8s qa0 = *(const bf8s*)(qrow);        // d 0..31
  bf8s qa1 = *(const bf8s*)(qrow + 32);   // d 32..63

  float mi[4] = {-1e30f, -1e30f, -1e30f, -1e30f};
  float li[4] = {0, 0, 0, 0};
  f32x4 oacc[4] = {};

  for (int kt = 0; kt < S_; kt += 32) {
    __syncthreads();
    {  // stage K tile (row-major, pad 72) and V tile (transposed)
      bf8s kv = *(const bf8s*)(Kb + base + (size_t)(kt + skey) * HID_ + sdg * 8);
      *(bf8s*)(&Kl[skey * 72 + sdg * 8]) = kv;
      bf8s vv = *(const bf8s*)(V + base + (size_t)(kt + skey) * HID_ + sdg * 8);
      #pragma unroll
      for (int j = 0; j < 8; ++j) Vt[(sdg * 8 + j) * 32 + skey] = vv[j];
    }
    __syncthreads();

    // scores: two 16x16 tiles (keys kt..+15, kt+16..+31)
    f32x4 s0 = {}, s1 = {};
    bf8s kb0 = *(const bf8s*)(&Kl[row16 * 72 + quad * 8]);
    bf8s kb1 = *(const bf8s*)(&Kl[row16 * 72 + 32 + quad * 8]);
    bf8s kb2 = *(const bf8s*)(&Kl[(16 + row16) * 72 + quad * 8]);
    bf8s kb3 = *(const bf8s*)(&Kl[(16 + row16) * 72 + 32 + quad * 8]);
    s0 = MFMA16(qa0, kb0, s0); s0 = MFMA16(qa1, kb1, s0);
    s1 = MFMA16(qa0, kb2, s1); s1 = MFMA16(qa1, kb3, s1);

    float p0[4], p1[4], mt[4], al[4], rs[4];
    #pragma unroll
    for (int r = 0; r < 4; ++r) {
      s0[r] *= scale; s1[r] *= scale;
      mt[r] = fmaxf(s0[r], s1[r]);
    }
    #pragma unroll
    for (int m = 1; m <= 8; m <<= 1)
      #pragma unroll
      for (int r = 0; r < 4; ++r) mt[r] = fmaxf(mt[r], __shfl_xor(mt[r], m));
    #pragma unroll
    for (int r = 0; r < 4; ++r) {
      float mn = fmaxf(mi[r], mt[r]);
      al[r] = expf(mi[r] - mn);
      mi[r] = mn;
      p0[r] = expf(s0[r] - mn);
      p1[r] = expf(s1[r] - mn);
      rs[r] = p0[r] + p1[r];
    }
    #pragma unroll
    for (int m = 1; m <= 8; m <<= 1)
      #pragma unroll
      for (int r = 0; r < 4; ++r) rs[r] += __shfl_xor(rs[r], m);
    #pragma unroll
    for (int r = 0; r < 4; ++r) li[r] = li[r] * al[r] + rs[r];
    #pragma unroll
    for (int dt = 0; dt < 4; ++dt)
      #pragma unroll
      for (int r = 0; r < 4; ++r) oacc[dt][r] *= al[r];

    // P: C-layout -> LDS -> A-layout
    #pragma unroll
    for (int r = 0; r < 4; ++r) {
      Pl[wave][(quad * 4 + r) * 32 + row16] = f2bf(p0[r]);
      Pl[wave][(quad * 4 + r) * 32 + 16 + row16] = f2bf(p1[r]);
    }
    bf8s pa = *(const bf8s*)(&Pl[wave][row16 * 32 + quad * 8]);
    #pragma unroll
    for (int dt = 0; dt < 4; ++dt) {
      bf8s vb2 = *(const bf8s*)(&Vt[(dt * 16 + row16) * 32 + quad * 8]);
      oacc[dt] = MFMA16(pa, vb2, oacc[dt]);
    }
  }

  float inv[4];
  #pragma unroll
  for (int r = 0; r < 4; ++r) inv[r] = 1.f / li[r];
  #pragma unroll
  for (int dt = 0; dt < 4; ++dt)
    #pragma unroll
    for (int r = 0; r < 4; ++r)
      O[base + (size_t)(q0 + wave * 16 + quad * 4 + r) * HID_ + dt * 16 + row16] =
          f2bf(oacc[dt][r] * inv[r]);
}

// ---------------- classifier ----------------
__global__ __launch_bounds__(256) void k_clf(const float* __restrict__ xf,
    const short* __restrict__ Wc, const float* __restrict__ cbias, float* out) {
  int i = threadIdx.x;  // 256 = 128 batches x 2 classes
  int b = i >> 1, c = i & 1;
  float s = 0.f;
  for (int k = 0; k < HID_; ++k)
    s += xf[(size_t)b * S_ * HID_ + k] * bf2f(Wc[c * HID_ + k]);
  out[b * 2 + c] = s + cbias[c];
}

// ---------------- launcher ----------------
extern "C" void kernel_launch(void* const* d_in, const int* in_sizes, int n_in,
                              void* d_out, int out_size, void* d_ws, size_t ws_size,
                              hipStream_t stream) {
  const int*   ids     = (const int*)d_in[0];
  const float* tok_emb = (const float*)d_in[1];
  const float* pos_emb = (const float*)d_in[2];
  const float* ln_g    = (const float*)d_in[3];
  const float* ln_bb   = (const float*)d_in[4];
  const float* qw      = (const float*)d_in[5];
  const float* qbias   = (const float*)d_in[6];
  const float* kw      = (const float*)d_in[7];
  const float* kbias   = (const float*)d_in[8];
  const float* vw      = (const float*)d_in[9];
  const float* vbias   = (const float*)d_in[10];
  const float* aow     = (const float*)d_in[11];
  const float* aobias  = (const float*)d_in[12];
  const float* iw      = (const float*)d_in[13];
  const float* ibias   = (const float*)d_in[14];
  const float* fow     = (const float*)d_in[15];
  const float* fbias   = (const float*)d_in[16];
  const float* ln1g    = (const float*)d_in[17];
  const float* ln1b    = (const float*)d_in[18];
  const float* ln2g    = (const float*)d_in[19];
  const float* ln2b    = (const float*)d_in[20];
  const float* clfw    = (const float*)d_in[21];
  const float* clfb    = (const float*)d_in[22];

  char* ws = (char*)d_ws;
  short* WQ  = (short*)ws;                                   // 393472 bf16 quantized weights
  float* scr = (float*)(ws + 917504);                        // 48 floats atomic scratch
  float* xf  = (float*)(ws + 1048576);                       // fp32 trunk  (33.5 MB)
  short* xb  = (short*)(ws + 1048576 + 33554432);            // bf16 trunk  (16.8 MB)
  short* qb_ = (short*)(ws + 1048576 + 33554432 + 16777216); // q/k/v/ctx bf16
  short* kb_ = qb_ + (size_t)M_ * HID_;
  short* vb_ = kb_ + (size_t)M_ * HID_;
  short* cb_ = vb_ + (size_t)M_ * HID_;
  short* hb_ = qb_;  // FF intermediate (65536x512 bf16) aliases q/k/v/ctx (dead by then)

  hipMemsetAsync(scr, 0, 48 * sizeof(float), stream);
  dim3 qg(16, 13);
  k_q1<<<qg, 256, 0, stream>>>(qw, kw, vw, aow, iw, fow, clfw, scr);
  k_q2<<<qg, 256, 0, stream>>>(qw, kw, vw, aow, iw, fow, clfw, scr);
  k_q3<<<qg, 256, 0, stream>>>(qw, kw, vw, aow, iw, fow, clfw, scr, WQ);

  k_embed<<<M_ / 4, 256, 0, stream>>>(ids, tok_emb, pos_emb, ln_g, ln_bb, xf, xb);

  for (int l = 0; l < 2; ++l) {
    const short* Wq = WQ + (size_t)(0 + l) * 16384;
    const short* Wk = WQ + (size_t)(2 + l) * 16384;
    const short* Wv = WQ + (size_t)(4 + l) * 16384;
    const short* Wa = WQ + (size_t)(6 + l) * 16384;
    const short* Wi = WQ + 131072 + (size_t)l * 65536;
    const short* Wf = WQ + 262144 + (size_t)l * 65536;

    k_linear<<<dim3(M_ / 64, 1), 256, 0, stream>>>(xb, Wq, qbias + l * HID_, 128, 128, 0,
                                                   qb_, nullptr, nullptr, nullptr, nullptr);
    k_linear<<<dim3(M_ / 64, 1), 256, 0, stream>>>(xb, Wk, kbias + l * HID_, 128, 128, 0,
                                                   kb_, nullptr, nullptr, nullptr, nullptr);
    k_linear<<<dim3(M_ / 64, 1), 256, 0, stream>>>(xb, Wv, vbias + l * HID_, 128, 128, 0,
                                                   vb_, nullptr, nullptr, nullptr, nullptr);
    k_attn<<<dim3(S_ / 64, 2, B_), 256, 0, stream>>>(qb_, kb_, vb_, cb_);
    k_linear<<<dim3(M_ / 64, 1), 256, 0, stream>>>(cb_, Wa, aobias + l * HID_, 128, 128, 2,
                                                   xb, xf, ln1g + l * HID_, ln1b + l * HID_, xf);
    k_linear<<<dim3(M_ / 64, 4), 256, 0, stream>>>(xb, Wi, ibias + l * 512, 128, 512, 1,
                                                   hb_, nullptr, nullptr, nullptr, nullptr);
    k_linear<<<dim3(M_ / 64, 1), 256, 0, stream>>>(hb_, Wf, fbias + l * HID_, 512, 128, 2,
                                                   xb, xf, ln2g + l * HID_, ln2b + l * HID_, xf);
  }

  k_clf<<<1, 256, 0, stream>>>(xf, WQ + 393216, clfb, (float*)d_out);
}

// Round 2
// 742.812 us; speedup vs baseline: 1.1648x; 1.1648x over previous
//
#include <hip/hip_runtime.h>

// ---------------- types / helpers ----------------
typedef short bf8s __attribute__((ext_vector_type(8)));   // 8 bf16 (4 VGPRs)
typedef float f32x4 __attribute__((ext_vector_type(4)));

#define MFMA16(a, b, c) __builtin_amdgcn_mfma_f32_16x16x32_bf16(a, b, c, 0, 0, 0)

constexpr int S_ = 512, HID_ = 128, B_ = 128, M_ = B_ * S_;

__device__ inline short f2bf(float f) {  // fp32 -> bf16 (RNE)
  unsigned u = __float_as_uint(f);
  u = (u + 0x7fffu + ((u >> 16) & 1u)) >> 16;
  return (short)u;
}
__device__ inline float bf2f(short s) {
  return __uint_as_float(((unsigned)(unsigned short)s) << 16);
}

// 1024-thread block reduction (16 waves). Caller may reuse immediately.
__device__ inline float block_red1024(float v, float* red) {
  #pragma unroll
  for (int m = 32; m >= 1; m >>= 1) v += __shfl_xor(v, m);
  __syncthreads();  // protect red[] from previous call's readers
  if ((threadIdx.x & 63) == 0) red[threadIdx.x >> 6] = v;
  __syncthreads();
  float t = 0.f;
  #pragma unroll
  for (int i = 0; i < 16; ++i) t += red[i];
  return t;
}

// matrix table. doff layout (shorts):
//  per-layer QKV contiguous: l*49152 + {q:0,k:16384,v:32768}
//  ao: 98304 + l*16384 ; iw: 131072 + l*65536 ; fow: 262144 + l*65536 ; clf: 393216
__device__ inline void mat_info(int mat, const float* qw, const float* kw,
                                const float* vw, const float* aow, const float* iw,
                                const float* fw, const float* cw,
                                const float** src, int* n, int* doff) {
  if (mat < 6) {
    int l = mat / 3, which = mat % 3;
    const float* t[3] = {qw, kw, vw};
    *src = t[which] + l * 16384; *n = 16384; *doff = l * 49152 + which * 16384;
  } else if (mat < 8) {
    int l = mat - 6;
    *src = aow + l * 16384; *n = 16384; *doff = 98304 + l * 16384;
  } else if (mat < 10) {
    *src = iw + (mat - 8) * 65536; *n = 65536; *doff = 131072 + (mat - 8) * 65536;
  } else if (mat < 12) {
    *src = fw + (mat - 10) * 65536; *n = 65536; *doff = 262144 + (mat - 10) * 65536;
  } else {
    *src = cw; *n = 256; *doff = 393216;
  }
}

// ---------------- ternary quantization: one kernel, 13 blocks ----------------
__global__ __launch_bounds__(1024) void k_quant(const float* qw, const float* kw,
    const float* vw, const float* aow, const float* iw, const float* fw,
    const float* cw, short* WQ) {
  __shared__ float red[16];
  const float* src; int n, doff;
  mat_info(blockIdx.x, qw, kw, vw, aow, iw, fw, cw, &src, &n, &doff);
  int tid = threadIdx.x;

  float s = 0.f;
  for (int i = tid; i < n; i += 1024) s += fabsf(src[i]);
  s = block_red1024(s, red);
  float delta = 0.7f * s / (float)n;

  float s2 = 0.f, c2 = 0.f;
  for (int i = tid; i < n; i += 1024) {
    float a = fabsf(src[i]);
    if (a > delta) { s2 += a; c2 += 1.f; }
  }
  s2 = block_red1024(s2, red);
  c2 = block_red1024(c2, red);
  float alpha = s2 / fmaxf(c2, 1.f);

  for (int i = tid; i < n; i += 1024) {
    float w = src[i];
    WQ[doff + i] = (fabsf(w) > delta) ? f2bf(w > 0.f ? alpha : -alpha) : (short)0;
  }
}

// ---------------- embedding + LN ----------------
__global__ __launch_bounds__(256) void k_embed(const int* __restrict__ ids,
    const float* __restrict__ tok, const float* __restrict__ pos,
    const float* __restrict__ g, const float* __restrict__ bb,
    float* xf, short* xb) {
  int wave = threadIdx.x >> 6, lane = threadIdx.x & 63;
  int t = blockIdx.x * 4 + wave;
  int s = t & (S_ - 1);
  int id = ids[t];
  float e0 = tok[(size_t)id * HID_ + lane] + pos[(size_t)s * HID_ + lane];
  float e1 = tok[(size_t)id * HID_ + 64 + lane] + pos[(size_t)s * HID_ + 64 + lane];
  float sum = e0 + e1, ssq = e0 * e0 + e1 * e1;
  #pragma unroll
  for (int m = 32; m >= 1; m >>= 1) {
    sum += __shfl_xor(sum, m);
    ssq += __shfl_xor(ssq, m);
  }
  float mean = sum / 128.f;
  float var = ssq / 128.f - mean * mean;
  float rs = rsqrtf(var + 1e-5f);
  float v0 = (e0 - mean) * rs * g[lane] + bb[lane];
  float v1 = (e1 - mean) * rs * g[64 + lane] + bb[64 + lane];
  size_t o = (size_t)t * HID_;
  xf[o + lane] = v0; xf[o + 64 + lane] = v1;
  xb[o + lane] = f2bf(v0); xb[o + 64 + lane] = f2bf(v1);
}

// ---------------- generic MFMA linear ----------------
// block = 128 tokens x 128 outs; wave = 32 tokens (2 A-frags) x 128 outs (16 C tiles)
// mode 0: bias -> bf16;  1: bias+relu -> bf16;
// mode 2: bias + residual + LayerNorm -> outf (fp32) + outb (bf16)  [grid.y==1]
// bias: if b1 != null, bias ptr selected by blockIdx.y (merged QKV), indexed 0..127;
//       else bias = b0 indexed by global col.
__global__ __launch_bounds__(256) void k_linear(
    const short* __restrict__ A, const short* __restrict__ W,
    const float* __restrict__ b0, const float* __restrict__ b1,
    const float* __restrict__ b2, int K, int out_stride, int mode,
    short* outb, const float* resid, const float* __restrict__ lng,
    const float* __restrict__ lnb, float* outf) {
  int lane = threadIdx.x & 63, wave = threadIdx.x >> 6;
  int row16 = lane & 15, quad = lane >> 4;
  int tok0 = blockIdx.x * 128 + wave * 32;
  int nbase = blockIdx.y * 128;

  f32x4 acc[2][8] = {};
  const short* a0 = A + (size_t)(tok0 + row16) * K + quad * 8;
  const short* a1 = A + (size_t)(tok0 + 16 + row16) * K + quad * 8;
  const short* wp = W + (size_t)(nbase + row16) * K + quad * 8;
  for (int kc = 0; kc < K; kc += 32) {
    bf8s av0 = *(const bf8s*)(a0 + kc);
    bf8s av1 = *(const bf8s*)(a1 + kc);
    #pragma unroll
    for (int ot = 0; ot < 8; ++ot) {
      bf8s b = *(const bf8s*)(wp + (size_t)ot * 16 * K + kc);
      acc[0][ot] = MFMA16(av0, b, acc[0][ot]);
      acc[1][ot] = MFMA16(av1, b, acc[1][ot]);
    }
  }

  const float* bp = b0;
  if (b1) bp = (blockIdx.y == 0) ? b0 : ((blockIdx.y == 1) ? b1 : b2);
  int bshift = b1 ? 0 : nbase;

  if (mode < 2) {
    #pragma unroll
    for (int g = 0; g < 2; ++g) {
      int m0 = tok0 + g * 16 + quad * 4;
      #pragma unroll
      for (int ot = 0; ot < 8; ++ot) {
        int col = ot * 16 + row16;
        float bi = bp[bshift + col];
        #pragma unroll
        for (int r = 0; r < 4; ++r) {
          float v = acc[g][ot][r] + bi;
          if (mode == 1) v = fmaxf(v, 0.f);
          outb[(size_t)(m0 + r) * out_stride + nbase + col] = f2bf(v);
        }
      }
    }
  } else {
    float sum[2][4] = {}, ssq[2][4] = {};
    #pragma unroll
    for (int g = 0; g < 2; ++g) {
      int m0 = tok0 + g * 16 + quad * 4;
      #pragma unroll
      for (int ot = 0; ot < 8; ++ot) {
        int col = ot * 16 + row16;
        float bi = bp[col];
        #pragma unroll
        for (int r = 0; r < 4; ++r) {
          float v = acc[g][ot][r] + bi + resid[(size_t)(m0 + r) * HID_ + col];
          acc[g][ot][r] = v;
          sum[g][r] += v; ssq[g][r] += v * v;
        }
      }
    }
    #pragma unroll
    for (int m = 1; m <= 8; m <<= 1)
      #pragma unroll
      for (int g = 0; g < 2; ++g)
        #pragma unroll
        for (int r = 0; r < 4; ++r) {
          sum[g][r] += __shfl_xor(sum[g][r], m);
          ssq[g][r] += __shfl_xor(ssq[g][r], m);
        }
    float mean[2][4], rstd[2][4];
    #pragma unroll
    for (int g = 0; g < 2; ++g)
      #pragma unroll
      for (int r = 0; r < 4; ++r) {
        mean[g][r] = sum[g][r] / 128.f;
        float var = ssq[g][r] / 128.f - mean[g][r] * mean[g][r];
        rstd[g][r] = rsqrtf(var + 1e-5f);
      }
    #pragma unroll
    for (int g = 0; g < 2; ++g) {
      int m0 = tok0 + g * 16 + quad * 4;
      #pragma unroll
      for (int ot = 0; ot < 8; ++ot) {
        int col = ot * 16 + row16;
        float gg = lng[col], bb2 = lnb[col];
        #pragma unroll
        for (int r = 0; r < 4; ++r) {
          float v = (acc[g][ot][r] - mean[g][r]) * rstd[g][r] * gg + bb2;
          size_t idx = (size_t)(m0 + r) * HID_ + col;
          outf[idx] = v;
          outb[idx] = f2bf(v);
        }
      }
    }
  }
}

// ---------------- V transpose: qkv[tok][256+h*64+d] -> Vt[(b,h,d)][s] ----------------
// grid = (S/64, H, B), block 256
__global__ __launch_bounds__(256) void k_vtrans(const short* __restrict__ qkv,
                                                short* __restrict__ Vt) {
  __shared__ short Vl[64 * 72];  // 64 s x 64 d, stride 72 (144B = 9x16B, b128-aligned)
  int tid = threadIdx.x;
  int b = blockIdx.z, h = blockIdx.y, s0 = blockIdx.x * 64;
  const short* src = qkv + (size_t)(b * S_ + s0) * 384 + 256 + h * 64;
  #pragma unroll
  for (int rep = 0; rep < 2; ++rep) {
    int i = rep * 256 + tid;
    int sl = i >> 3, dg = i & 7;
    bf8s v = *(const bf8s*)(src + (size_t)sl * 384 + dg * 8);
    *(bf8s*)(&Vl[sl * 72 + dg * 8]) = v;
  }
  __syncthreads();
  short* dst = Vt + ((size_t)(b * 2 + h) * 64) * S_ + s0;
  #pragma unroll
  for (int rep = 0; rep < 2; ++rep) {
    int i = rep * 256 + tid;
    int d = i >> 3, sg = i & 7;
    bf8s o;
    #pragma unroll
    for (int j = 0; j < 8; ++j) o[j] = Vl[(sg * 8 + j) * 72 + d];
    *(bf8s*)(dst + (size_t)d * S_ + sg * 8) = o;
  }
}

// ---------------- flash attention: no staging, no __syncthreads ----------------
// grid = (S/64, H=2, B); block = 256 (4 waves x 16 queries); 64-key tiles
__global__ __launch_bounds__(256) void k_attn(const short* __restrict__ qkv,
    const short* __restrict__ Vt, short* __restrict__ O) {
  constexpr float scale = 0.125f;  // 1/sqrt(64)
  __shared__ short Pl[4][16 * 88];  // per-wave P stash, stride 88 (176B = 11x16B)

  int tid = threadIdx.x, lane = tid & 63, wave = tid >> 6;
  int row16 = lane & 15, quad = lane >> 4;
  int b = blockIdx.z, h = blockIdx.y, q0 = blockIdx.x * 64;

  const short* qbase = qkv + (size_t)b * S_ * 384 + h * 64;         // Q cols
  const short* kbase = qkv + (size_t)b * S_ * 384 + 128 + h * 64;   // K cols
  const short* vtb   = Vt + (size_t)(b * 2 + h) * 64 * S_;

  const short* qrow = qbase + (size_t)(q0 + wave * 16 + row16) * 384 + quad * 8;
  bf8s qa0 = *(const bf8s*)(qrow);
  bf8s qa1 = *(const bf8s*)(qrow + 32);

  float mi[4] = {-1e30f, -1e30f, -1e30f, -1e30f};
  float li[4] = {0, 0, 0, 0};
  f32x4 oacc[4] = {};
  short* myP = &Pl[wave][0];

  for (int kt = 0; kt < S_; kt += 64) {
    // ---- scores: 4 key-subtiles of 16, K=64 (2 MFMA each) ----
    f32x4 sc[4] = {};
    #pragma unroll
    for (int ks = 0; ks < 4; ++ks) {
      const short* kr = kbase + (size_t)(kt + ks * 16 + row16) * 384 + quad * 8;
      bf8s k0 = *(const bf8s*)(kr);
      bf8s k1 = *(const bf8s*)(kr + 32);
      sc[ks] = MFMA16(qa0, k0, sc[ks]);
      sc[ks] = MFMA16(qa1, k1, sc[ks]);
    }

    // ---- online softmax ----
    float mt[4], al[4], rs[4];
    #pragma unroll
    for (int r = 0; r < 4; ++r) {
      float m01 = fmaxf(sc[0][r], sc[1][r]);
      float m23 = fmaxf(sc[2][r], sc[3][r]);
      mt[r] = fmaxf(m01, m23) * scale;
    }
    #pragma unroll
    for (int m = 1; m <= 8; m <<= 1)
      #pragma unroll
      for (int r = 0; r < 4; ++r) mt[r] = fmaxf(mt[r], __shfl_xor(mt[r], m));
    #pragma unroll
    for (int r = 0; r < 4; ++r) {
      float mn = fmaxf(mi[r], mt[r]);
      al[r] = __expf(mi[r] - mn);
      mi[r] = mn;
      rs[r] = 0.f;
    }
    float p[4][4];
    #pragma unroll
    for (int ks = 0; ks < 4; ++ks)
      #pragma unroll
      for (int r = 0; r < 4; ++r) {
        p[ks][r] = __expf(sc[ks][r] * scale - mi[r]);
        rs[r] += p[ks][r];
      }
    #pragma unroll
    for (int m = 1; m <= 8; m <<= 1)
      #pragma unroll
      for (int r = 0; r < 4; ++r) rs[r] += __shfl_xor(rs[r], m);
    #pragma unroll
    for (int r = 0; r < 4; ++r) li[r] = li[r] * al[r] + rs[r];
    #pragma unroll
    for (int dt = 0; dt < 4; ++dt)
      #pragma unroll
      for (int r = 0; r < 4; ++r) oacc[dt][r] *= al[r];

    // ---- P: C-layout -> per-wave LDS -> A-layout ----
    #pragma unroll
    for (int ks = 0; ks < 4; ++ks)
      #pragma unroll
      for (int r = 0; r < 4; ++r)
        myP[(quad * 4 + r) * 88 + ks * 16 + row16] = f2bf(p[ks][r]);
    bf8s pa0 = *(const bf8s*)(&myP[row16 * 88 + quad * 8]);
    bf8s pa1 = *(const bf8s*)(&myP[row16 * 88 + 32 + quad * 8]);

    // ---- PV ----
    #pragma unroll
    for (int dt = 0; dt < 4; ++dt) {
      const short* vr = vtb + (size_t)(dt * 16 + row16) * S_ + kt + quad * 8;
      bf8s v0 = *(const bf8s*)(vr);
      bf8s v1 = *(const bf8s*)(vr + 32);
      oacc[dt] = MFMA16(pa0, v0, oacc[dt]);
      oacc[dt] = MFMA16(pa1, v1, oacc[dt]);
    }
  }

  float inv[4];
  #pragma unroll
  for (int r = 0; r < 4; ++r) inv[r] = 1.f / li[r];
  size_t obase = (size_t)(b * S_ + q0 + wave * 16 + quad * 4) * HID_ + h * 64;
  #pragma unroll
  for (int dt = 0; dt < 4; ++dt)
    #pragma unroll
    for (int r = 0; r < 4; ++r)
      O[obase + (size_t)r * HID_ + dt * 16 + row16] = f2bf(oacc[dt][r] * inv[r]);
}

// ---------------- classifier ----------------
__global__ __launch_bounds__(256) void k_clf(const float* __restrict__ xf,
    const short* __restrict__ Wc, const float* __restrict__ cbias, float* out) {
  int i = threadIdx.x;  // 256 = 128 batches x 2 classes
  int b = i >> 1, c = i & 1;
  float s = 0.f;
  for (int k = 0; k < HID_; ++k)
    s += xf[(size_t)b * S_ * HID_ + k] * bf2f(Wc[c * HID_ + k]);
  out[b * 2 + c] = s + cbias[c];
}

// ---------------- launcher ----------------
extern "C" void kernel_launch(void* const* d_in, const int* in_sizes, int n_in,
                              void* d_out, int out_size, void* d_ws, size_t ws_size,
                              hipStream_t stream) {
  const int*   ids     = (const int*)d_in[0];
  const float* tok_emb = (const float*)d_in[1];
  const float* pos_emb = (const float*)d_in[2];
  const float* ln_g    = (const float*)d_in[3];
  const float* ln_bb   = (const float*)d_in[4];
  const float* qw      = (const float*)d_in[5];
  const float* qbias   = (const float*)d_in[6];
  const float* kw      = (const float*)d_in[7];
  const float* kbias   = (const float*)d_in[8];
  const float* vw      = (const float*)d_in[9];
  const float* vbias   = (const float*)d_in[10];
  const float* aow     = (const float*)d_in[11];
  const float* aobias  = (const float*)d_in[12];
  const float* iw      = (const float*)d_in[13];
  const float* ibias   = (const float*)d_in[14];
  const float* fow     = (const float*)d_in[15];
  const float* fbias   = (const float*)d_in[16];
  const float* ln1g    = (const float*)d_in[17];
  const float* ln1b    = (const float*)d_in[18];
  const float* ln2g    = (const float*)d_in[19];
  const float* ln2b    = (const float*)d_in[20];
  const float* clfw    = (const float*)d_in[21];
  const float* clfb    = (const float*)d_in[22];

  char* ws = (char*)d_ws;
  short* WQ  = (short*)ws;                                   // 393472 bf16 (787KB)
  float* xf  = (float*)(ws + 1048576);                       // fp32 trunk (33.5MB)
  short* xb  = (short*)(ws + 1048576 + 33554432);            // bf16 trunk (16.8MB)
  short* Vt  = xb;                                           // aliases xb (dead phases)
  short* qkv = (short*)(ws + 1048576 + 33554432 + 16777216); // [tok][384] (50.3MB)
  short* cb_ = qkv + (size_t)M_ * 384;                       // ctx [tok][128] (16.8MB)
  short* hb_ = qkv;  // FF intermediate [tok][512] (67MB) aliases qkv+cb (dead then)

  k_quant<<<13, 1024, 0, stream>>>(qw, kw, vw, aow, iw, fow, clfw, WQ);
  k_embed<<<M_ / 4, 256, 0, stream>>>(ids, tok_emb, pos_emb, ln_g, ln_bb, xf, xb);

  for (int l = 0; l < 2; ++l) {
    const short* Wqkv = WQ + (size_t)l * 49152;
    const short* Wa   = WQ + 98304 + (size_t)l * 16384;
    const short* Wi   = WQ + 131072 + (size_t)l * 65536;
    const short* Wf   = WQ + 262144 + (size_t)l * 65536;

    // merged QKV: N=384, bias selected per blockIdx.y
    k_linear<<<dim3(M_ / 128, 3), 256, 0, stream>>>(
        xb, Wqkv, qbias + l * HID_, kbias + l * HID_, vbias + l * HID_,
        128, 384, 0, qkv, nullptr, nullptr, nullptr, nullptr);
    k_vtrans<<<dim3(S_ / 64, 2, B_), 256, 0, stream>>>(qkv, Vt);
    k_attn<<<dim3(S_ / 64, 2, B_), 256, 0, stream>>>(qkv, Vt, cb_);
    k_linear<<<dim3(M_ / 128, 1), 256, 0, stream>>>(
        cb_, Wa, aobias + l * HID_, nullptr, nullptr, 128, 128, 2,
        xb, xf, ln1g + l * HID_, ln1b + l * HID_, xf);
    k_linear<<<dim3(M_ / 128, 4), 256, 0, stream>>>(
        xb, Wi, ibias + l * 512, nullptr, nullptr, 128, 512, 1,
        hb_, nullptr, nullptr, nullptr, nullptr);
    k_linear<<<dim3(M_ / 128, 1), 256, 0, stream>>>(
        hb_, Wf, fbias + l * HID_, nullptr, nullptr, 512, 128, 2,
        xb, xf, ln2g + l * HID_, ln2b + l * HID_, xf);
  }

  k_clf<<<1, 256, 0, stream>>>(xf, WQ + 393216, clfb, (float*)d_out);
}

// Round 4
// 541.608 us; speedup vs baseline: 1.5976x; 1.3715x over previous
//
#include <hip/hip_runtime.h>

// ---------------- types / helpers ----------------
typedef short bf8s __attribute__((ext_vector_type(8)));   // 8 bf16 (4 VGPRs)
typedef float f32x4 __attribute__((ext_vector_type(4)));

#define MFMA16(a, b, c) __builtin_amdgcn_mfma_f32_16x16x32_bf16(a, b, c, 0, 0, 0)

constexpr int S_ = 512, HID_ = 128, B_ = 128, M_ = B_ * S_;

__device__ inline short f2bf(float f) {  // fp32 -> bf16 (RNE)
  unsigned u = __float_as_uint(f);
  u = (u + 0x7fffu + ((u >> 16) & 1u)) >> 16;
  return (short)u;
}
__device__ inline float bf2f(short s) {
  return __uint_as_float(((unsigned)(unsigned short)s) << 16);
}

// 1024-thread block reduction (16 waves).
__device__ inline float block_red1024(float v, float* red) {
  #pragma unroll
  for (int m = 32; m >= 1; m >>= 1) v += __shfl_xor(v, m);
  __syncthreads();
  if ((threadIdx.x & 63) == 0) red[threadIdx.x >> 6] = v;
  __syncthreads();
  float t = 0.f;
  #pragma unroll
  for (int i = 0; i < 16; ++i) t += red[i];
  return t;
}

// matrix table. doff layout (shorts):
//  per-layer QKV contiguous: l*49152 + {q:0,k:16384,v:32768}
//  ao: 98304 + l*16384 ; iw: 131072 + l*65536 ; fow: 262144 + l*65536 ; clf: 393216
__device__ inline void mat_info(int mat, const float* qw, const float* kw,
                                const float* vw, const float* aow, const float* iw,
                                const float* fw, const float* cw,
                                const float** src, int* n, int* doff) {
  if (mat < 6) {
    int l = mat / 3, which = mat % 3;
    const float* t[3] = {qw, kw, vw};
    *src = t[which] + l * 16384; *n = 16384; *doff = l * 49152 + which * 16384;
  } else if (mat < 8) {
    int l = mat - 6;
    *src = aow + l * 16384; *n = 16384; *doff = 98304 + l * 16384;
  } else if (mat < 10) {
    *src = iw + (mat - 8) * 65536; *n = 65536; *doff = 131072 + (mat - 8) * 65536;
  } else if (mat < 12) {
    *src = fw + (mat - 10) * 65536; *n = 65536; *doff = 262144 + (mat - 10) * 65536;
  } else {
    *src = cw; *n = 256; *doff = 393216;
  }
}

// ---------------- ternary quantization ----------------
__global__ __launch_bounds__(1024) void k_quant(const float* qw, const float* kw,
    const float* vw, const float* aow, const float* iw, const float* fw,
    const float* cw, short* WQ) {
  __shared__ float red[16];
  const float* src; int n, doff;
  mat_info(blockIdx.x, qw, kw, vw, aow, iw, fw, cw, &src, &n, &doff);
  int tid = threadIdx.x;

  float s = 0.f;
  for (int i = tid; i < n; i += 1024) s += fabsf(src[i]);
  s = block_red1024(s, red);
  float delta = 0.7f * s / (float)n;

  float s2 = 0.f, c2 = 0.f;
  for (int i = tid; i < n; i += 1024) {
    float a = fabsf(src[i]);
    if (a > delta) { s2 += a; c2 += 1.f; }
  }
  s2 = block_red1024(s2, red);
  c2 = block_red1024(c2, red);
  float alpha = s2 / fmaxf(c2, 1.f);

  for (int i = tid; i < n; i += 1024) {
    float w = src[i];
    WQ[doff + i] = (fabsf(w) > delta) ? f2bf(w > 0.f ? alpha : -alpha) : (short)0;
  }
}

// ---------------- embedding + LN (bf16 trunk only) ----------------
__global__ __launch_bounds__(256) void k_embed(const int* __restrict__ ids,
    const float* __restrict__ tok, const float* __restrict__ pos,
    const float* __restrict__ g, const float* __restrict__ bb, short* xb) {
  int wave = threadIdx.x >> 6, lane = threadIdx.x & 63;
  int t = blockIdx.x * 4 + wave;
  int s = t & (S_ - 1);
  int id = ids[t];
  float e0 = tok[(size_t)id * HID_ + lane] + pos[(size_t)s * HID_ + lane];
  float e1 = tok[(size_t)id * HID_ + 64 + lane] + pos[(size_t)s * HID_ + 64 + lane];
  float sum = e0 + e1, ssq = e0 * e0 + e1 * e1;
  #pragma unroll
  for (int m = 32; m >= 1; m >>= 1) {
    sum += __shfl_xor(sum, m);
    ssq += __shfl_xor(ssq, m);
  }
  float mean = sum / 128.f;
  float var = ssq / 128.f - mean * mean;
  float rs = rsqrtf(var + 1e-5f);
  size_t o = (size_t)t * HID_;
  xb[o + lane]      = f2bf((e0 - mean) * rs * g[lane] + bb[lane]);
  xb[o + 64 + lane] = f2bf((e1 - mean) * rs * g[64 + lane] + bb[64 + lane]);
}

// ---------------- templated MFMA linear, W staged in LDS ----------------
// block = 128 tokens x 128 outs; wave = 32 tokens x 128 outs (16 C tiles)
// MODE 0: bias -> bf16;  1: bias+relu -> bf16;
// MODE 2: bias + bf16 residual + LayerNorm -> bf16 (outb may alias resid)
template <int K, int MODE>
__global__ __launch_bounds__(256) void k_linear_t(
    const short* __restrict__ A, const short* __restrict__ W,
    const float* __restrict__ b0, const float* __restrict__ b1,
    const float* __restrict__ b2, int out_stride,
    short* outb, const short* resid,
    const float* __restrict__ lng, const float* __restrict__ lnb) {
  __shared__ short Wl[128 * 136];  // stride 136 shorts = 68 words
  int tid = threadIdx.x, lane = tid & 63, wave = tid >> 6;
  int row16 = lane & 15, quad = lane >> 4;
  int tok0 = blockIdx.x * 128 + wave * 32;
  int nbase = blockIdx.y * 128;

  f32x4 acc[2][8] = {};
  const short* a0 = A + (size_t)(tok0 + row16) * K + quad * 8;
  const short* a1 = a0 + (size_t)16 * K;
  const short* wbase = W + (size_t)nbase * K;

  for (int kc0 = 0; kc0 < K; kc0 += 128) {
    if (kc0) __syncthreads();
    {  // stage 128x128 W chunk: 2 threads per row, 64 shorts each
      int r = tid >> 1, half = tid & 1;
      const short* src = wbase + (size_t)r * K + kc0 + half * 64;
      short* dst = &Wl[r * 136 + half * 64];
      #pragma unroll
      for (int j = 0; j < 8; ++j)   // FIXED (was j<4: staged only half the tile)
        *(bf8s*)(dst + j * 8) = *(const bf8s*)(src + j * 8);
    }
    __syncthreads();
    #pragma unroll
    for (int ki = 0; ki < 4; ++ki) {
      bf8s av0 = *(const bf8s*)(a0 + kc0 + ki * 32);
      bf8s av1 = *(const bf8s*)(a1 + kc0 + ki * 32);
      #pragma unroll
      for (int ot = 0; ot < 8; ++ot) {
        bf8s b = *(const bf8s*)(&Wl[(ot * 16 + row16) * 136 + ki * 32 + quad * 8]);
        acc[0][ot] = MFMA16(av0, b, acc[0][ot]);
        acc[1][ot] = MFMA16(av1, b, acc[1][ot]);
      }
    }
  }

  const float* bp = b0;
  if (b1) bp = (blockIdx.y == 0) ? b0 : ((blockIdx.y == 1) ? b1 : b2);
  int bshift = b1 ? 0 : nbase;

  if (MODE < 2) {
    #pragma unroll
    for (int g = 0; g < 2; ++g) {
      int m0 = tok0 + g * 16 + quad * 4;
      #pragma unroll
      for (int ot = 0; ot < 8; ++ot) {
        int col = ot * 16 + row16;
        float bi = bp[bshift + col];
        #pragma unroll
        for (int r = 0; r < 4; ++r) {
          float v = acc[g][ot][r] + bi;
          if (MODE == 1) v = fmaxf(v, 0.f);
          outb[(size_t)(m0 + r) * out_stride + nbase + col] = f2bf(v);
        }
      }
    }
  } else {
    float sum[2][4] = {}, ssq[2][4] = {};
    #pragma unroll
    for (int g = 0; g < 2; ++g) {
      int m0 = tok0 + g * 16 + quad * 4;
      #pragma unroll
      for (int ot = 0; ot < 8; ++ot) {
        int col = ot * 16 + row16;
        float bi = bp[col];
        #pragma unroll
        for (int r = 0; r < 4; ++r) {
          float v = acc[g][ot][r] + bi + bf2f(resid[(size_t)(m0 + r) * HID_ + col]);
          acc[g][ot][r] = v;
          sum[g][r] += v; ssq[g][r] += v * v;
        }
      }
    }
    #pragma unroll
    for (int m = 1; m <= 8; m <<= 1)
      #pragma unroll
      for (int g = 0; g < 2; ++g)
        #pragma unroll
        for (int r = 0; r < 4; ++r) {
          sum[g][r] += __shfl_xor(sum[g][r], m);
          ssq[g][r] += __shfl_xor(ssq[g][r], m);
        }
    #pragma unroll
    for (int g = 0; g < 2; ++g) {
      int m0 = tok0 + g * 16 + quad * 4;
      float mean[4], rstd[4];
      #pragma unroll
      for (int r = 0; r < 4; ++r) {
        mean[r] = sum[g][r] / 128.f;
        float var = ssq[g][r] / 128.f - mean[r] * mean[r];
        rstd[r] = rsqrtf(var + 1e-5f);
      }
      #pragma unroll
      for (int ot = 0; ot < 8; ++ot) {
        int col = ot * 16 + row16;
        float gg = lng[col], bb2 = lnb[col];
        #pragma unroll
        for (int r = 0; r < 4; ++r) {
          float v = (acc[g][ot][r] - mean[r]) * rstd[r] * gg + bb2;
          outb[(size_t)(m0 + r) * HID_ + col] = f2bf(v);
        }
      }
    }
  }
}

// ---------------- flash attention: K/V LDS-resident per (b,h) ----------------
// grid = 256 (= b*2+h), block = 512 (8 waves x 64 queries each)
// LDS: Kl 18432 + Vtl 17408 + Pl 18432 = 54272 B (< 64 KB)
__global__ __launch_bounds__(512) void k_attn(const short* __restrict__ qkv,
                                              short* __restrict__ O) {
  constexpr float scale = 0.125f;  // 1/sqrt(64)
  __shared__ short Kl[128 * 72];    // 128 keys x 64 d, stride 72
  __shared__ short Vtl[64 * 136];   // 64 d x 128 keys, stride 136
  __shared__ short Pl[8][16 * 72];  // per-wave P stash

  int tid = threadIdx.x, lane = tid & 63, wave = tid >> 6;
  int row16 = lane & 15, quad = lane >> 4;
  int b = blockIdx.x >> 1, h = blockIdx.x & 1;
  const short* base  = qkv + (size_t)b * S_ * 384;
  const short* kbase = base + 128 + h * 64;
  const short* vbase = base + 256 + h * 64;

  // Q fragments: wave owns queries wave*64 .. wave*64+63 (4 frags of 16)
  bf8s qa[4][2];
  #pragma unroll
  for (int qf = 0; qf < 4; ++qf) {
    const short* qrow = base + h * 64 +
        (size_t)(wave * 64 + qf * 16 + row16) * 384 + quad * 8;
    qa[qf][0] = *(const bf8s*)(qrow);
    qa[qf][1] = *(const bf8s*)(qrow + 32);
  }

  float mi[4][4], li[4][4];
  f32x4 oacc[4][4] = {};
  #pragma unroll
  for (int qf = 0; qf < 4; ++qf)
    #pragma unroll
    for (int r = 0; r < 4; ++r) { mi[qf][r] = -1e30f; li[qf][r] = 0.f; }
  short* myP = &Pl[wave][0];

  for (int kt0 = 0; kt0 < S_; kt0 += 128) {  // 4 stages of 128 keys
    if (kt0) __syncthreads();
    {  // stage K rows (coalesced, b128 writes)
      #pragma unroll
      for (int it = 0; it < 2; ++it) {
        int i = it * 512 + tid;
        int krow = i >> 3, dg = i & 7;
        *(bf8s*)(&Kl[krow * 72 + dg * 8]) =
            *(const bf8s*)(kbase + (size_t)(kt0 + krow) * 384 + dg * 8);
      }
      // stage V transposed (key-major lanes)
      #pragma unroll
      for (int it = 0; it < 2; ++it) {
        int i = it * 512 + tid;
        int key = i & 127, dg = i >> 7;
        bf8s v = *(const bf8s*)(vbase + (size_t)(kt0 + key) * 384 + dg * 8);
        #pragma unroll
        for (int j = 0; j < 8; ++j) Vtl[(dg * 8 + j) * 136 + key] = v[j];
      }
    }
    __syncthreads();

    #pragma unroll
    for (int kh = 0; kh < 2; ++kh) {  // two 64-key tiles per stage
      int ktL = kh * 64;
      bf8s kfr[4][2], vfr[4][2];
      #pragma unroll
      for (int ks = 0; ks < 4; ++ks) {
        const short* kp = &Kl[(ktL + ks * 16 + row16) * 72 + quad * 8];
        kfr[ks][0] = *(const bf8s*)(kp);
        kfr[ks][1] = *(const bf8s*)(kp + 32);
      }
      #pragma unroll
      for (int dt = 0; dt < 4; ++dt) {
        const short* vp = &Vtl[(dt * 16 + row16) * 136 + ktL + quad * 8];
        vfr[dt][0] = *(const bf8s*)(vp);
        vfr[dt][1] = *(const bf8s*)(vp + 32);
      }

      #pragma unroll
      for (int qf = 0; qf < 4; ++qf) {
        f32x4 sc[4] = {};
        #pragma unroll
        for (int ks = 0; ks < 4; ++ks) {
          sc[ks] = MFMA16(qa[qf][0], kfr[ks][0], sc[ks]);
          sc[ks] = MFMA16(qa[qf][1], kfr[ks][1], sc[ks]);
        }
        float mt[4], al[4], rs[4], p[4][4];
        #pragma unroll
        for (int r = 0; r < 4; ++r) {
          float m01 = fmaxf(sc[0][r], sc[1][r]);
          float m23 = fmaxf(sc[2][r], sc[3][r]);
          mt[r] = fmaxf(m01, m23) * scale;
        }
        #pragma unroll
        for (int m = 1; m <= 8; m <<= 1)
          #pragma unroll
          for (int r = 0; r < 4; ++r) mt[r] = fmaxf(mt[r], __shfl_xor(mt[r], m));
        #pragma unroll
        for (int r = 0; r < 4; ++r) {
          float mn = fmaxf(mi[qf][r], mt[r]);
          al[r] = __expf(mi[qf][r] - mn);
          mi[qf][r] = mn;
          rs[r] = 0.f;
        }
        #pragma unroll
        for (int ks = 0; ks < 4; ++ks)
          #pragma unroll
          for (int r = 0; r < 4; ++r) {
            p[ks][r] = __expf(sc[ks][r] * scale - mi[qf][r]);
            rs[r] += p[ks][r];
          }
        #pragma unroll
        for (int m = 1; m <= 8; m <<= 1)
          #pragma unroll
          for (int r = 0; r < 4; ++r) rs[r] += __shfl_xor(rs[r], m);
        #pragma unroll
        for (int r = 0; r < 4; ++r) li[qf][r] = li[qf][r] * al[r] + rs[r];
        #pragma unroll
        for (int dt = 0; dt < 4; ++dt)
          #pragma unroll
          for (int r = 0; r < 4; ++r) oacc[qf][dt][r] *= al[r];

        #pragma unroll
        for (int ks = 0; ks < 4; ++ks)
          #pragma unroll
          for (int r = 0; r < 4; ++r)
            myP[(quad * 4 + r) * 72 + ks * 16 + row16] = f2bf(p[ks][r]);
        bf8s pa0 = *(const bf8s*)(&myP[row16 * 72 + quad * 8]);
        bf8s pa1 = *(const bf8s*)(&myP[row16 * 72 + 32 + quad * 8]);
        #pragma unroll
        for (int dt = 0; dt < 4; ++dt) {
          oacc[qf][dt] = MFMA16(pa0, vfr[dt][0], oacc[qf][dt]);
          oacc[qf][dt] = MFMA16(pa1, vfr[dt][1], oacc[qf][dt]);
        }
      }
    }
  }

  #pragma unroll
  for (int qf = 0; qf < 4; ++qf) {
    float inv[4];
    #pragma unroll
    for (int r = 0; r < 4; ++r) inv[r] = 1.f / li[qf][r];
    size_t trow = (size_t)(b * S_ + wave * 64 + qf * 16 + quad * 4);
    #pragma unroll
    for (int dt = 0; dt < 4; ++dt)
      #pragma unroll
      for (int r = 0; r < 4; ++r)
        O[(trow + r) * HID_ + h * 64 + dt * 16 + row16] =
            f2bf(oacc[qf][dt][r] * inv[r]);
  }
}

// ---------------- classifier ----------------
__global__ __launch_bounds__(256) void k_clf(const short* __restrict__ xb,
    const short* __restrict__ Wc, const float* __restrict__ cbias, float* out) {
  int i = threadIdx.x;  // 256 = 128 batches x 2 classes
  int b = i >> 1, c = i & 1;
  float s = 0.f;
  for (int k = 0; k < HID_; ++k)
    s += bf2f(xb[(size_t)b * S_ * HID_ + k]) * bf2f(Wc[c * HID_ + k]);
  out[b * 2 + c] = s + cbias[c];
}

// ---------------- launcher ----------------
extern "C" void kernel_launch(void* const* d_in, const int* in_sizes, int n_in,
                              void* d_out, int out_size, void* d_ws, size_t ws_size,
                              hipStream_t stream) {
  const int*   ids     = (const int*)d_in[0];
  const float* tok_emb = (const float*)d_in[1];
  const float* pos_emb = (const float*)d_in[2];
  const float* ln_g    = (const float*)d_in[3];
  const float* ln_bb   = (const float*)d_in[4];
  const float* qw      = (const float*)d_in[5];
  const float* qbias   = (const float*)d_in[6];
  const float* kw      = (const float*)d_in[7];
  const float* kbias   = (const float*)d_in[8];
  const float* vw      = (const float*)d_in[9];
  const float* vbias   = (const float*)d_in[10];
  const float* aow     = (const float*)d_in[11];
  const float* aobias  = (const float*)d_in[12];
  const float* iw      = (const float*)d_in[13];
  const float* ibias   = (const float*)d_in[14];
  const float* fow     = (const float*)d_in[15];
  const float* fbias   = (const float*)d_in[16];
  const float* ln1g    = (const float*)d_in[17];
  const float* ln1b    = (const float*)d_in[18];
  const float* ln2g    = (const float*)d_in[19];
  const float* ln2b    = (const float*)d_in[20];
  const float* clfw    = (const float*)d_in[21];
  const float* clfb    = (const float*)d_in[22];

  char* ws = (char*)d_ws;
  short* WQ  = (short*)ws;                                   // 787 KB quantized weights
  short* xb  = (short*)(ws + 1048576);                       // bf16 trunk (16.8 MB)
  short* qkv = (short*)(ws + 1048576 + 16777216);            // [tok][384] (50.3 MB)
  short* cb_ = qkv + (size_t)M_ * 384;                       // ctx [tok][128] (16.8 MB)
  short* hb_ = qkv;  // FF intermediate [tok][512] (67 MB) aliases qkv+cb (dead then)

  k_quant<<<13, 1024, 0, stream>>>(qw, kw, vw, aow, iw, fow, clfw, WQ);
  k_embed<<<M_ / 4, 256, 0, stream>>>(ids, tok_emb, pos_emb, ln_g, ln_bb, xb);

  for (int l = 0; l < 2; ++l) {
    const short* Wqkv = WQ + (size_t)l * 49152;
    const short* Wa   = WQ + 98304 + (size_t)l * 16384;
    const short* Wi   = WQ + 131072 + (size_t)l * 65536;
    const short* Wf   = WQ + 262144 + (size_t)l * 65536;

    k_linear_t<128, 0><<<dim3(M_ / 128, 3), 256, 0, stream>>>(
        xb, Wqkv, qbias + l * HID_, kbias + l * HID_, vbias + l * HID_,
        384, qkv, nullptr, nullptr, nullptr);
    k_attn<<<256, 512, 0, stream>>>(qkv, cb_);
    k_linear_t<128, 2><<<dim3(M_ / 128, 1), 256, 0, stream>>>(
        cb_, Wa, aobias + l * HID_, nullptr, nullptr,
        128, xb, xb, ln1g + l * HID_, ln1b + l * HID_);
    k_linear_t<128, 1><<<dim3(M_ / 128, 4), 256, 0, stream>>>(
        xb, Wi, ibias + l * 512, nullptr, nullptr,
        512, hb_, nullptr, nullptr, nullptr);
    k_linear_t<512, 2><<<dim3(M_ / 128, 1), 256, 0, stream>>>(
        hb_, Wf, fbias + l * HID_, nullptr, nullptr,
        128, xb, xb, ln2g + l * HID_, ln2b + l * HID_);
  }

  k_clf<<<1, 256, 0, stream>>>(xb, WQ + 393216, clfb, (float*)d_out);
}

// Round 5
// 534.378 us; speedup vs baseline: 1.6192x; 1.0135x over previous
//
#include <hip/hip_runtime.h>

// ---------------- types / helpers ----------------
typedef short bf8s __attribute__((ext_vector_type(8)));   // 8 bf16 (4 VGPRs)
typedef float f32x4 __attribute__((ext_vector_type(4)));

#define MFMA16(a, b, c) __builtin_amdgcn_mfma_f32_16x16x32_bf16(a, b, c, 0, 0, 0)

constexpr int S_ = 512, HID_ = 128, B_ = 128, M_ = B_ * S_;

__device__ inline short f2bf(float f) {  // fp32 -> bf16 (RNE)
  unsigned u = __float_as_uint(f);
  u = (u + 0x7fffu + ((u >> 16) & 1u)) >> 16;
  return (short)u;
}
__device__ inline float bf2f(short s) {
  return __uint_as_float(((unsigned)(unsigned short)s) << 16);
}

// 1024-thread block reduction (16 waves).
__device__ inline float block_red1024(float v, float* red) {
  #pragma unroll
  for (int m = 32; m >= 1; m >>= 1) v += __shfl_xor(v, m);
  __syncthreads();
  if ((threadIdx.x & 63) == 0) red[threadIdx.x >> 6] = v;
  __syncthreads();
  float t = 0.f;
  #pragma unroll
  for (int i = 0; i < 16; ++i) t += red[i];
  return t;
}

// matrix table. doff layout (shorts):
//  per-layer QKV contiguous: l*49152 + {q:0,k:16384,v:32768}
//  ao: 98304 + l*16384 ; iw: 131072 + l*65536 ; fow: 262144 + l*65536 ; clf: 393216
__device__ inline void mat_info(int mat, const float* qw, const float* kw,
                                const float* vw, const float* aow, const float* iw,
                                const float* fw, const float* cw,
                                const float** src, int* n, int* doff) {
  if (mat < 6) {
    int l = mat / 3, which = mat % 3;
    const float* t[3] = {qw, kw, vw};
    *src = t[which] + l * 16384; *n = 16384; *doff = l * 49152 + which * 16384;
  } else if (mat < 8) {
    int l = mat - 6;
    *src = aow + l * 16384; *n = 16384; *doff = 98304 + l * 16384;
  } else if (mat < 10) {
    *src = iw + (mat - 8) * 65536; *n = 65536; *doff = 131072 + (mat - 8) * 65536;
  } else if (mat < 12) {
    *src = fw + (mat - 10) * 65536; *n = 65536; *doff = 262144 + (mat - 10) * 65536;
  } else {
    *src = cw; *n = 256; *doff = 393216;
  }
}

// ---------------- ternary quantization ----------------
__global__ __launch_bounds__(1024) void k_quant(const float* qw, const float* kw,
    const float* vw, const float* aow, const float* iw, const float* fw,
    const float* cw, short* WQ) {
  __shared__ float red[16];
  const float* src; int n, doff;
  mat_info(blockIdx.x, qw, kw, vw, aow, iw, fw, cw, &src, &n, &doff);
  int tid = threadIdx.x;

  float s = 0.f;
  for (int i = tid; i < n; i += 1024) s += fabsf(src[i]);
  s = block_red1024(s, red);
  float delta = 0.7f * s / (float)n;

  float s2 = 0.f, c2 = 0.f;
  for (int i = tid; i < n; i += 1024) {
    float a = fabsf(src[i]);
    if (a > delta) { s2 += a; c2 += 1.f; }
  }
  s2 = block_red1024(s2, red);
  c2 = block_red1024(c2, red);
  float alpha = s2 / fmaxf(c2, 1.f);

  for (int i = tid; i < n; i += 1024) {
    float w = src[i];
    WQ[doff + i] = (fabsf(w) > delta) ? f2bf(w > 0.f ? alpha : -alpha) : (short)0;
  }
}

// ---------------- embedding + LN (bf16 trunk only) ----------------
__global__ __launch_bounds__(256) void k_embed(const int* __restrict__ ids,
    const float* __restrict__ tok, const float* __restrict__ pos,
    const float* __restrict__ g, const float* __restrict__ bb, short* xb) {
  int wave = threadIdx.x >> 6, lane = threadIdx.x & 63;
  int t = blockIdx.x * 4 + wave;
  int s = t & (S_ - 1);
  int id = ids[t];
  float e0 = tok[(size_t)id * HID_ + lane] + pos[(size_t)s * HID_ + lane];
  float e1 = tok[(size_t)id * HID_ + 64 + lane] + pos[(size_t)s * HID_ + 64 + lane];
  float sum = e0 + e1, ssq = e0 * e0 + e1 * e1;
  #pragma unroll
  for (int m = 32; m >= 1; m >>= 1) {
    sum += __shfl_xor(sum, m);
    ssq += __shfl_xor(ssq, m);
  }
  float mean = sum / 128.f;
  float var = ssq / 128.f - mean * mean;
  float rs = rsqrtf(var + 1e-5f);
  size_t o = (size_t)t * HID_;
  xb[o + lane]      = f2bf((e0 - mean) * rs * g[lane] + bb[lane]);
  xb[o + 64 + lane] = f2bf((e1 - mean) * rs * g[64 + lane] + bb[64 + lane]);
}

// ---------------- templated MFMA linear, W staged in LDS ----------------
// block = 128 tokens x 128 outs; wave = 32 tokens x 128 outs (16 C tiles)
// MODE 0: bias -> bf16;  1: bias+relu -> bf16;
// MODE 2: bias + bf16 residual + LayerNorm -> bf16 (outb may alias resid)
template <int K, int MODE>
__global__ __launch_bounds__(256) void k_linear_t(
    const short* __restrict__ A, const short* __restrict__ W,
    const float* __restrict__ b0, const float* __restrict__ b1,
    const float* __restrict__ b2, int out_stride,
    short* outb, const short* resid,
    const float* __restrict__ lng, const float* __restrict__ lnb) {
  __shared__ short Wl[128 * 136];  // stride 136 shorts = 68 words
  int tid = threadIdx.x, lane = tid & 63, wave = tid >> 6;
  int row16 = lane & 15, quad = lane >> 4;
  int tok0 = blockIdx.x * 128 + wave * 32;
  int nbase = blockIdx.y * 128;

  f32x4 acc[2][8] = {};
  const short* a0 = A + (size_t)(tok0 + row16) * K + quad * 8;
  const short* a1 = a0 + (size_t)16 * K;
  const short* wbase = W + (size_t)nbase * K;

  for (int kc0 = 0; kc0 < K; kc0 += 128) {
    if (kc0) __syncthreads();
    {  // stage 128x128 W chunk: 2 threads per row, 64 shorts each
      int r = tid >> 1, half = tid & 1;
      const short* src = wbase + (size_t)r * K + kc0 + half * 64;
      short* dst = &Wl[r * 136 + half * 64];
      #pragma unroll
      for (int j = 0; j < 8; ++j)
        *(bf8s*)(dst + j * 8) = *(const bf8s*)(src + j * 8);
    }
    __syncthreads();
    #pragma unroll
    for (int ki = 0; ki < 4; ++ki) {
      bf8s av0 = *(const bf8s*)(a0 + kc0 + ki * 32);
      bf8s av1 = *(const bf8s*)(a1 + kc0 + ki * 32);
      #pragma unroll
      for (int ot = 0; ot < 8; ++ot) {
        bf8s b = *(const bf8s*)(&Wl[(ot * 16 + row16) * 136 + ki * 32 + quad * 8]);
        acc[0][ot] = MFMA16(av0, b, acc[0][ot]);
        acc[1][ot] = MFMA16(av1, b, acc[1][ot]);
      }
    }
  }

  const float* bp = b0;
  if (b1) bp = (blockIdx.y == 0) ? b0 : ((blockIdx.y == 1) ? b1 : b2);
  int bshift = b1 ? 0 : nbase;

  if (MODE < 2) {
    #pragma unroll
    for (int g = 0; g < 2; ++g) {
      int m0 = tok0 + g * 16 + quad * 4;
      #pragma unroll
      for (int ot = 0; ot < 8; ++ot) {
        int col = ot * 16 + row16;
        float bi = bp[bshift + col];
        #pragma unroll
        for (int r = 0; r < 4; ++r) {
          float v = acc[g][ot][r] + bi;
          if (MODE == 1) v = fmaxf(v, 0.f);
          outb[(size_t)(m0 + r) * out_stride + nbase + col] = f2bf(v);
        }
      }
    }
  } else {
    float sum[2][4] = {}, ssq[2][4] = {};
    #pragma unroll
    for (int g = 0; g < 2; ++g) {
      int m0 = tok0 + g * 16 + quad * 4;
      #pragma unroll
      for (int ot = 0; ot < 8; ++ot) {
        int col = ot * 16 + row16;
        float bi = bp[col];
        #pragma unroll
        for (int r = 0; r < 4; ++r) {
          float v = acc[g][ot][r] + bi + bf2f(resid[(size_t)(m0 + r) * HID_ + col]);
          acc[g][ot][r] = v;
          sum[g][r] += v; ssq[g][r] += v * v;
        }
      }
    }
    #pragma unroll
    for (int m = 1; m <= 8; m <<= 1)
      #pragma unroll
      for (int g = 0; g < 2; ++g)
        #pragma unroll
        for (int r = 0; r < 4; ++r) {
          sum[g][r] += __shfl_xor(sum[g][r], m);
          ssq[g][r] += __shfl_xor(ssq[g][r], m);
        }
    #pragma unroll
    for (int g = 0; g < 2; ++g) {
      int m0 = tok0 + g * 16 + quad * 4;
      float mean[4], rstd[4];
      #pragma unroll
      for (int r = 0; r < 4; ++r) {
        mean[r] = sum[g][r] / 128.f;
        float var = ssq[g][r] / 128.f - mean[r] * mean[r];
        rstd[r] = rsqrtf(var + 1e-5f);
      }
      #pragma unroll
      for (int ot = 0; ot < 8; ++ot) {
        int col = ot * 16 + row16;
        float gg = lng[col], bb2 = lnb[col];
        #pragma unroll
        for (int r = 0; r < 4; ++r) {
          float v = (acc[g][ot][r] - mean[r]) * rstd[r] * gg + bb2;
          outb[(size_t)(m0 + r) * HID_ + col] = f2bf(v);
        }
      }
    }
  }
}

// ---------------- flash attention: K/V LDS-resident per (b,h) ----------------
// grid = 256 (= b*2+h), block = 512 (8 waves x 64 queries each)
// LDS: Kl 18432 + Vtl 17408 + Pl 18432 = 54272 B
// __launch_bounds__(512, 2): 8-wave block = 2 waves/EU -> 256-VGPR cap.
// Round-4 failure mode: default heuristic capped VGPR at 128 and spilled
// ~250 MB/dispatch to scratch (WRITE_SIZE 203 MB vs 33.5 MB ideal).
__global__ __launch_bounds__(512, 2) void k_attn(const short* __restrict__ qkv,
                                                 short* __restrict__ O) {
  constexpr float scale = 0.125f;  // 1/sqrt(64)
  __shared__ short Kl[128 * 72];    // 128 keys x 64 d, stride 72
  __shared__ short Vtl[64 * 136];   // 64 d x 128 keys, stride 136
  __shared__ short Pl[8][16 * 72];  // per-wave P stash

  int tid = threadIdx.x, lane = tid & 63, wave = tid >> 6;
  int row16 = lane & 15, quad = lane >> 4;
  int b = blockIdx.x >> 1, h = blockIdx.x & 1;
  const short* base  = qkv + (size_t)b * S_ * 384;
  const short* kbase = base + 128 + h * 64;
  const short* vbase = base + 256 + h * 64;

  // Q fragments: wave owns queries wave*64 .. wave*64+63 (4 frags of 16)
  bf8s qa[4][2];
  #pragma unroll
  for (int qf = 0; qf < 4; ++qf) {
    const short* qrow = base + h * 64 +
        (size_t)(wave * 64 + qf * 16 + row16) * 384 + quad * 8;
    qa[qf][0] = *(const bf8s*)(qrow);
    qa[qf][1] = *(const bf8s*)(qrow + 32);
  }

  float mi[4][4], li[4][4];
  f32x4 oacc[4][4] = {};
  #pragma unroll
  for (int qf = 0; qf < 4; ++qf)
    #pragma unroll
    for (int r = 0; r < 4; ++r) { mi[qf][r] = -1e30f; li[qf][r] = 0.f; }
  short* myP = &Pl[wave][0];

  for (int kt0 = 0; kt0 < S_; kt0 += 128) {  // 4 stages of 128 keys
    if (kt0) __syncthreads();
    {  // stage K rows (coalesced, b128 writes)
      #pragma unroll
      for (int it = 0; it < 2; ++it) {
        int i = it * 512 + tid;
        int krow = i >> 3, dg = i & 7;
        *(bf8s*)(&Kl[krow * 72 + dg * 8]) =
            *(const bf8s*)(kbase + (size_t)(kt0 + krow) * 384 + dg * 8);
      }
      // stage V transposed (key-major lanes)
      #pragma unroll
      for (int it = 0; it < 2; ++it) {
        int i = it * 512 + tid;
        int key = i & 127, dg = i >> 7;
        bf8s v = *(const bf8s*)(vbase + (size_t)(kt0 + key) * 384 + dg * 8);
        #pragma unroll
        for (int j = 0; j < 8; ++j) Vtl[(dg * 8 + j) * 136 + key] = v[j];
      }
    }
    __syncthreads();

    #pragma unroll
    for (int kh = 0; kh < 2; ++kh) {  // two 64-key tiles per stage
      int ktL = kh * 64;
      bf8s kfr[4][2], vfr[4][2];
      #pragma unroll
      for (int ks = 0; ks < 4; ++ks) {
        const short* kp = &Kl[(ktL + ks * 16 + row16) * 72 + quad * 8];
        kfr[ks][0] = *(const bf8s*)(kp);
        kfr[ks][1] = *(const bf8s*)(kp + 32);
      }
      #pragma unroll
      for (int dt = 0; dt < 4; ++dt) {
        const short* vp = &Vtl[(dt * 16 + row16) * 136 + ktL + quad * 8];
        vfr[dt][0] = *(const bf8s*)(vp);
        vfr[dt][1] = *(const bf8s*)(vp + 32);
      }

      #pragma unroll
      for (int qf = 0; qf < 4; ++qf) {
        f32x4 sc[4] = {};
        #pragma unroll
        for (int ks = 0; ks < 4; ++ks) {
          sc[ks] = MFMA16(qa[qf][0], kfr[ks][0], sc[ks]);
          sc[ks] = MFMA16(qa[qf][1], kfr[ks][1], sc[ks]);
        }
        float mt[4], al[4], rs[4];
        #pragma unroll
        for (int r = 0; r < 4; ++r) {
          #pragma unroll
          for (int ks = 0; ks < 4; ++ks) sc[ks][r] *= scale;
          float m01 = fmaxf(sc[0][r], sc[1][r]);
          float m23 = fmaxf(sc[2][r], sc[3][r]);
          mt[r] = fmaxf(m01, m23);
        }
        #pragma unroll
        for (int m = 1; m <= 8; m <<= 1)
          #pragma unroll
          for (int r = 0; r < 4; ++r) mt[r] = fmaxf(mt[r], __shfl_xor(mt[r], m));
        #pragma unroll
        for (int r = 0; r < 4; ++r) {
          float mn = fmaxf(mi[qf][r], mt[r]);
          al[r] = __expf(mi[qf][r] - mn);
          mi[qf][r] = mn;
          rs[r] = 0.f;
        }
        // P: exp -> LDS stash immediately (no p[][] register array)
        #pragma unroll
        for (int ks = 0; ks < 4; ++ks)
          #pragma unroll
          for (int r = 0; r < 4; ++r) {
            float pv = __expf(sc[ks][r] - mi[qf][r]);
            rs[r] += pv;
            myP[(quad * 4 + r) * 72 + ks * 16 + row16] = f2bf(pv);
          }
        #pragma unroll
        for (int m = 1; m <= 8; m <<= 1)
          #pragma unroll
          for (int r = 0; r < 4; ++r) rs[r] += __shfl_xor(rs[r], m);
        #pragma unroll
        for (int r = 0; r < 4; ++r) li[qf][r] = li[qf][r] * al[r] + rs[r];
        #pragma unroll
        for (int dt = 0; dt < 4; ++dt)
          #pragma unroll
          for (int r = 0; r < 4; ++r) oacc[qf][dt][r] *= al[r];

        bf8s pa0 = *(const bf8s*)(&myP[row16 * 72 + quad * 8]);
        bf8s pa1 = *(const bf8s*)(&myP[row16 * 72 + 32 + quad * 8]);
        #pragma unroll
        for (int dt = 0; dt < 4; ++dt) {
          oacc[qf][dt] = MFMA16(pa0, vfr[dt][0], oacc[qf][dt]);
          oacc[qf][dt] = MFMA16(pa1, vfr[dt][1], oacc[qf][dt]);
        }
      }
    }
  }

  #pragma unroll
  for (int qf = 0; qf < 4; ++qf) {
    float inv[4];
    #pragma unroll
    for (int r = 0; r < 4; ++r) inv[r] = 1.f / li[qf][r];
    size_t trow = (size_t)(b * S_ + wave * 64 + qf * 16 + quad * 4);
    #pragma unroll
    for (int dt = 0; dt < 4; ++dt)
      #pragma unroll
      for (int r = 0; r < 4; ++r)
        O[(trow + r) * HID_ + h * 64 + dt * 16 + row16] =
            f2bf(oacc[qf][dt][r] * inv[r]);
  }
}

// ---------------- classifier ----------------
__global__ __launch_bounds__(256) void k_clf(const short* __restrict__ xb,
    const short* __restrict__ Wc, const float* __restrict__ cbias, float* out) {
  int i = threadIdx.x;  // 256 = 128 batches x 2 classes
  int b = i >> 1, c = i & 1;
  float s = 0.f;
  for (int k = 0; k < HID_; ++k)
    s += bf2f(xb[(size_t)b * S_ * HID_ + k]) * bf2f(Wc[c * HID_ + k]);
  out[b * 2 + c] = s + cbias[c];
}

// ---------------- launcher ----------------
extern "C" void kernel_launch(void* const* d_in, const int* in_sizes, int n_in,
                              void* d_out, int out_size, void* d_ws, size_t ws_size,
                              hipStream_t stream) {
  const int*   ids     = (const int*)d_in[0];
  const float* tok_emb = (const float*)d_in[1];
  const float* pos_emb = (const float*)d_in[2];
  const float* ln_g    = (const float*)d_in[3];
  const float* ln_bb   = (const float*)d_in[4];
  const float* qw      = (const float*)d_in[5];
  const float* qbias   = (const float*)d_in[6];
  const float* kw      = (const float*)d_in[7];
  const float* kbias   = (const float*)d_in[8];
  const float* vw      = (const float*)d_in[9];
  const float* vbias   = (const float*)d_in[10];
  const float* aow     = (const float*)d_in[11];
  const float* aobias  = (const float*)d_in[12];
  const float* iw      = (const float*)d_in[13];
  const float* ibias   = (const float*)d_in[14];
  const float* fow     = (const float*)d_in[15];
  const float* fbias   = (const float*)d_in[16];
  const float* ln1g    = (const float*)d_in[17];
  const float* ln1b    = (const float*)d_in[18];
  const float* ln2g    = (const float*)d_in[19];
  const float* ln2b    = (const float*)d_in[20];
  const float* clfw    = (const float*)d_in[21];
  const float* clfb    = (const float*)d_in[22];

  char* ws = (char*)d_ws;
  short* WQ  = (short*)ws;                                   // 787 KB quantized weights
  short* xb  = (short*)(ws + 1048576);                       // bf16 trunk (16.8 MB)
  short* qkv = (short*)(ws + 1048576 + 16777216);            // [tok][384] (50.3 MB)
  short* cb_ = qkv + (size_t)M_ * 384;                       // ctx [tok][128] (16.8 MB)
  short* hb_ = qkv;  // FF intermediate [tok][512] (67 MB) aliases qkv+cb (dead then)

  k_quant<<<13, 1024, 0, stream>>>(qw, kw, vw, aow, iw, fow, clfw, WQ);
  k_embed<<<M_ / 4, 256, 0, stream>>>(ids, tok_emb, pos_emb, ln_g, ln_bb, xb);

  for (int l = 0; l < 2; ++l) {
    const short* Wqkv = WQ + (size_t)l * 49152;
    const short* Wa   = WQ + 98304 + (size_t)l * 16384;
    const short* Wi   = WQ + 131072 + (size_t)l * 65536;
    const short* Wf   = WQ + 262144 + (size_t)l * 65536;

    k_linear_t<128, 0><<<dim3(M_ / 128, 3), 256, 0, stream>>>(
        xb, Wqkv, qbias + l * HID_, kbias + l * HID_, vbias + l * HID_,
        384, qkv, nullptr, nullptr, nullptr);
    k_attn<<<256, 512, 0, stream>>>(qkv, cb_);
    k_linear_t<128, 2><<<dim3(M_ / 128, 1), 256, 0, stream>>>(
        cb_, Wa, aobias + l * HID_, nullptr, nullptr,
        128, xb, xb, ln1g + l * HID_, ln1b + l * HID_);
    k_linear_t<128, 1><<<dim3(M_ / 128, 4), 256, 0, stream>>>(
        xb, Wi, ibias + l * 512, nullptr, nullptr,
        512, hb_, nullptr, nullptr, nullptr);
    k_linear_t<512, 2><<<dim3(M_ / 128, 1), 256, 0, stream>>>(
        hb_, Wf, fbias + l * HID_, nullptr, nullptr,
        128, xb, xb, ln2g + l * HID_, ln2b + l * HID_);
  }

  k_clf<<<1, 256, 0, stream>>>(xb, WQ + 393216, clfb, (float*)d_out);
}